// Round 8
// baseline (320.401 us; speedup 1.0000x reference)
//
#include <hip/hip_runtime.h>
#include <hip/hip_bf16.h>
#include <math.h>

#define Bsz 2
#define Sq  2048
#define Dm  2048
#define Hn  16
#define KVn 4
#define HDn 128

typedef __attribute__((ext_vector_type(8))) short bf16x8;
typedef __attribute__((ext_vector_type(4))) float f32x4;
typedef __attribute__((ext_vector_type(4))) unsigned int u32x4;

__device__ __forceinline__ short f2b(float f) {
    __hip_bfloat16 h = __float2bfloat16(f);
    return *reinterpret_cast<short*>(&h);
}
__device__ __forceinline__ float b2f(short s) {
    __hip_bfloat16 h = *reinterpret_cast<__hip_bfloat16*>(&s);
    return __bfloat162float(h);
}
// pack two f32 -> one u32 of 2 bf16 (lo, hi); validated vs reference in R6
__device__ __forceinline__ unsigned pk2(float lo, float hh) {
    unsigned r;
    asm("v_cvt_pk_bf16_f32 %0, %1, %2" : "=v"(r) : "v"(lo), "v"(hh));
    return r;
}

// ------------- FUSED prep: x->bf16, weight transpose, cos/sin table -------------
// Blocks [0,NB_F2B): x elementwise. [NB_F2B, +NB_WC): weight transpose.
// [.., +NB_TCS): rope table tcs[d][gr] = {cos, sin}, d=0..63, gr=b*Sq+s.
#define NB_F2B 8192
#define NB_WC  10240   // 160 x 64
#define NB_TCS 1024    // 64*4096/256
__global__ __launch_bounds__(256) void prep_kernel(
    const float* __restrict__ X, short* __restrict__ Y,
    const float* __restrict__ wq, const float* __restrict__ wk,
    const float* __restrict__ wv, const float* __restrict__ wo,
    short* __restrict__ wqkvT, short* __restrict__ woT,
    const int* __restrict__ pos_ids, float* __restrict__ tcs)
{
    __shared__ float t[32][33];
    const int bid = blockIdx.x;
    const int tid = threadIdx.x;

    if (bid < NB_F2B) {
        const int i = bid * 256 + tid;
        float4 v = ((const float4*)X)[i];
        short4 o;
        o.x = f2b(v.x); o.y = f2b(v.y); o.z = f2b(v.z); o.w = f2b(v.w);
        ((short4*)Y)[i] = o;
        return;
    }
    if (bid >= NB_F2B + NB_WC) {
        // rope table: idx = d*4096 + gr
        const int idx = (bid - NB_F2B - NB_WC) * 256 + tid;
        const int d = idx >> 12, gr = idx & 4095;
        const int pos = pos_ids[gr];
        const float e   = -(float)(2 * d) * (1.0f / (float)HDn);
        const float inv = exp2f(e * 18.931568569324174f);   // log2(500000)
        const float f   = (float)pos * inv;
        float sn, c;
        sincosf(f, &sn, &c);
        float2 cs; cs.x = c; cs.y = sn;
        ((float2*)tcs)[idx] = cs;
        return;
    }

    const int wb = bid - NB_F2B;
    const int n0 = (wb % 160) * 32;   // global output row
    const int k0 = (wb / 160) * 32;
    const int tx = tid & 31, ty = tid >> 5;

    const float* W; int Nsec, nloc; short* dst;
    if (n0 < 2048)      { W = wq; Nsec = 2048; nloc = n0;        dst = wqkvT + (size_t)n0 * Dm; }
    else if (n0 < 2560) { W = wk; Nsec = 512;  nloc = n0 - 2048; dst = wqkvT + (size_t)n0 * Dm; }
    else if (n0 < 3072) { W = wv; Nsec = 512;  nloc = n0 - 2560; dst = wqkvT + (size_t)n0 * Dm; }
    else                { W = wo; Nsec = 2048; nloc = n0 - 3072; dst = woT + (size_t)(n0 - 3072) * Dm; }

#pragma unroll
    for (int r = 0; r < 4; ++r) {
        const int row = ty + 8 * r;
        t[row][tx] = W[(size_t)(k0 + row) * Nsec + nloc + tx];
    }
    __syncthreads();
#pragma unroll
    for (int r = 0; r < 4; ++r) {
        const int row = ty + 8 * r;
        dst[(size_t)row * Dm + k0 + tx] = f2b(t[tx][row]);
    }
}

// ---------------- QKV GEMM with fused in-register RoPE epilogue ----------------
// C = xb(4096x2048) * wqkvT(3072x2048)^T. Column fragment mapping puts the rope
// pair (d, d+64) in adjacent j-registers of each lane:
//   col(j) = (j&1)*64 + wn*32 + (j>>1)*16 + m16      (bijective over 0..127)
// Col-tile bx: 0..15 -> Q head bx (rope, qscale); 16..19 -> K head bx-16 (rope);
// 20..23 -> V head bx-20 (plain bf16 into C3v[gr][kv*128+col]).
__global__ __launch_bounds__(256) void gemm_qkv_kernel(
    const short* __restrict__ A, const short* __restrict__ Bt,
    short* __restrict__ Qb, short* __restrict__ Kbp, short* __restrict__ C3v,
    const float* __restrict__ tcs, float qscale)
{
    __shared__ __align__(16) short As[128 * 64];
    __shared__ __align__(16) short Bs[128 * 64];

    const int K = Dm, Mg = Bsz * Sq;
    const int tid  = threadIdx.x;
    const int w    = tid >> 6;
    const int lane = tid & 63;
    const int m16  = lane & 15;
    const int g4   = lane >> 4;
    const int wm   = w >> 1, wn = w & 1;

    // XCD swizzle (nwg = 24*32 = 768, %8 == 0)
    const int nwg = gridDim.x * gridDim.y;
    const int lin = blockIdx.y * gridDim.x + blockIdx.x;
    const int qq  = nwg >> 3;
    const int sw  = (lin & 7) * qq + (lin >> 3);
    const int bx  = sw % gridDim.x;
    const int by  = sw / gridDim.x;

    const int row0 = by * 128;
    const int col0 = bx * 128;

    const short* Ab = A  + (size_t)row0 * K;
    const short* Bb = Bt + (size_t)col0 * K;

    const int trow = tid >> 3;
    const int soct = (tid & 7) ^ (trow & 7);

    f32x4 acc[4][4];
#pragma unroll
    for (int i = 0; i < 4; ++i)
#pragma unroll
        for (int j = 0; j < 4; ++j) acc[i][j] = (f32x4){0.f, 0.f, 0.f, 0.f};

    for (int k0 = 0; k0 < K; k0 += 64) {
#pragma unroll
        for (int r = 0; r < 4; ++r) {
            const short* gp = Ab + (size_t)(r * 32 + trow) * K + k0 + soct * 8;
            short* lp = &As[(size_t)(r * 256 + w * 64) * 8];
            __builtin_amdgcn_global_load_lds(
                (const __attribute__((address_space(1))) void*)gp,
                (__attribute__((address_space(3))) void*)lp, 16, 0, 0);
        }
#pragma unroll
        for (int r = 0; r < 4; ++r) {
            const short* gp = Bb + (size_t)(r * 32 + trow) * K + k0 + soct * 8;
            short* lp = &Bs[(size_t)(r * 256 + w * 64) * 8];
            __builtin_amdgcn_global_load_lds(
                (const __attribute__((address_space(1))) void*)gp,
                (__attribute__((address_space(3))) void*)lp, 16, 0, 0);
        }
        __syncthreads();

#pragma unroll
        for (int kc = 0; kc < 2; ++kc) {
            bf16x8 a[4], b[4];
            const int swz = (kc * 4 + g4) ^ (m16 & 7);
#pragma unroll
            for (int s = 0; s < 4; ++s) {
                const int rowA = wm * 64 + s * 16 + m16;
                a[s] = *(const bf16x8*)&As[rowA * 64 + swz * 8];
                const int rowB = (s & 1) * 64 + wn * 32 + (s >> 1) * 16 + m16;
                b[s] = *(const bf16x8*)&Bs[rowB * 64 + swz * 8];
            }
#pragma unroll
            for (int i = 0; i < 4; ++i)
#pragma unroll
                for (int j = 0; j < 4; ++j)
                    acc[i][j] = __builtin_amdgcn_mfma_f32_16x16x32_bf16(
                        a[i], b[j], acc[i][j], 0, 0, 0);
        }
        __syncthreads();
    }

    // ---- fused epilogue ----
    const int dloc = wn * 32 + m16;          // d for jp=0; +16 for jp=1 (0..63)
    if (bx < 20) {
        const bool isQ = bx < 16;
        const int hh = isQ ? bx : bx - 16;
        const int NH = isQ ? Hn : KVn;
        short* Yb = isQ ? Qb : Kbp;
        const float scale = isQ ? qscale : 1.0f;
#pragma unroll
        for (int i = 0; i < 4; ++i) {
            const int gr0 = row0 + wm * 64 + i * 16 + g4 * 4;
            const int bb = gr0 >> 11, ss = gr0 & 2047;
            short* op = Yb + (((size_t)bb * NH + hh) * Sq + ss) * HDn;
#pragma unroll
            for (int jp = 0; jp < 2; ++jp) {
                const int d = dloc + jp * 16;
                const float4 t0 = *(const float4*)&tcs[((size_t)d * 4096 + gr0) * 2];
                const float4 t1 = *(const float4*)&tcs[((size_t)d * 4096 + gr0 + 2) * 2];
                const float cc0 = t0.x, sn0 = t0.y, cc1 = t0.z, sn1 = t0.w;
                const float cc2 = t1.x, sn2 = t1.y, cc3 = t1.z, sn3 = t1.w;
#pragma unroll
                for (int r = 0; r < 4; ++r) {
                    const float cc = (r == 0) ? cc0 : (r == 1) ? cc1 : (r == 2) ? cc2 : cc3;
                    const float sn = (r == 0) ? sn0 : (r == 1) ? sn1 : (r == 2) ? sn2 : sn3;
                    const float x1 = acc[i][2 * jp][r];
                    const float x2 = acc[i][2 * jp + 1][r];
                    op[(size_t)r * HDn + d]      = f2b((x1 * cc - x2 * sn) * scale);
                    op[(size_t)r * HDn + d + 64] = f2b((x2 * cc + x1 * sn) * scale);
                }
            }
        }
    } else {
        const int kvh = bx - 20;
#pragma unroll
        for (int i = 0; i < 4; ++i) {
            const int gr0 = row0 + wm * 64 + i * 16 + g4 * 4;
#pragma unroll
            for (int j = 0; j < 4; ++j) {
                const int col = (j & 1) * 64 + wn * 32 + (j >> 1) * 16 + m16;
#pragma unroll
                for (int r = 0; r < 4; ++r)
                    C3v[(size_t)(gr0 + r) * 512 + kvh * 128 + col] = f2b(acc[i][j][r]);
            }
        }
    }
}

// ---------------- output-projection GEMM (fp32 out), same frag mapping ----------------
__global__ __launch_bounds__(256) void gemm_o_kernel(
    const short* __restrict__ A, const short* __restrict__ Bt,
    float* __restrict__ C, int M, int N, int K)
{
    __shared__ __align__(16) short As[128 * 64];
    __shared__ __align__(16) short Bs[128 * 64];

    const int tid  = threadIdx.x;
    const int w    = tid >> 6;
    const int lane = tid & 63;
    const int m16  = lane & 15;
    const int g4   = lane >> 4;
    const int wm   = w >> 1, wn = w & 1;

    // XCD swizzle (nwg = 16*32 = 512, %8 == 0)
    const int nwg = gridDim.x * gridDim.y;
    const int lin = blockIdx.y * gridDim.x + blockIdx.x;
    const int qq  = nwg >> 3;
    const int sw  = (lin & 7) * qq + (lin >> 3);
    const int bx  = sw % gridDim.x;
    const int by  = sw / gridDim.x;

    const int row0 = by * 128;
    const int col0 = bx * 128;

    const short* Ab = A  + (size_t)row0 * K;
    const short* Bb = Bt + (size_t)col0 * K;

    const int trow = tid >> 3;
    const int soct = (tid & 7) ^ (trow & 7);

    f32x4 acc[4][4];
#pragma unroll
    for (int i = 0; i < 4; ++i)
#pragma unroll
        for (int j = 0; j < 4; ++j) acc[i][j] = (f32x4){0.f, 0.f, 0.f, 0.f};

    for (int k0 = 0; k0 < K; k0 += 64) {
#pragma unroll
        for (int r = 0; r < 4; ++r) {
            const short* gp = Ab + (size_t)(r * 32 + trow) * K + k0 + soct * 8;
            short* lp = &As[(size_t)(r * 256 + w * 64) * 8];
            __builtin_amdgcn_global_load_lds(
                (const __attribute__((address_space(1))) void*)gp,
                (__attribute__((address_space(3))) void*)lp, 16, 0, 0);
        }
#pragma unroll
        for (int r = 0; r < 4; ++r) {
            const short* gp = Bb + (size_t)(r * 32 + trow) * K + k0 + soct * 8;
            short* lp = &Bs[(size_t)(r * 256 + w * 64) * 8];
            __builtin_amdgcn_global_load_lds(
                (const __attribute__((address_space(1))) void*)gp,
                (__attribute__((address_space(3))) void*)lp, 16, 0, 0);
        }
        __syncthreads();

#pragma unroll
        for (int kc = 0; kc < 2; ++kc) {
            bf16x8 a[4], b[4];
            const int swz = (kc * 4 + g4) ^ (m16 & 7);
#pragma unroll
            for (int s = 0; s < 4; ++s) {
                const int rowA = wm * 64 + s * 16 + m16;
                a[s] = *(const bf16x8*)&As[rowA * 64 + swz * 8];
                const int rowB = (s & 1) * 64 + wn * 32 + (s >> 1) * 16 + m16;
                b[s] = *(const bf16x8*)&Bs[rowB * 64 + swz * 8];
            }
#pragma unroll
            for (int i = 0; i < 4; ++i)
#pragma unroll
                for (int j = 0; j < 4; ++j)
                    acc[i][j] = __builtin_amdgcn_mfma_f32_16x16x32_bf16(
                        a[i], b[j], acc[i][j], 0, 0, 0);
        }
        __syncthreads();
    }

#pragma unroll
    for (int i = 0; i < 4; ++i) {
        const int mbase = row0 + wm * 64 + i * 16 + g4 * 4;
#pragma unroll
        for (int j = 0; j < 4; ++j) {
            const int n = col0 + (j & 1) * 64 + wn * 32 + (j >> 1) * 16 + m16;
#pragma unroll
            for (int r = 0; r < 4; ++r)
                C[(size_t)(mbase + r) * N + n] = acc[i][j][r];
        }
    }
}

// ------------- V-only transpose: C3v (B*Sq x 512) -> (B,KV,HD,S) bf16 -------------
__global__ __launch_bounds__(256) void vconv_kernel(
    const short* __restrict__ C3v, short* __restrict__ Vt)
{
    __shared__ short t[32][34];
    const int bk = blockIdx.z;
    const int b  = bk >> 2, kv = bk & 3;
    const int s0 = blockIdx.x * 32;
    const int d0 = blockIdx.y * 32;
    const int tx = threadIdx.x, ty = threadIdx.y;

#pragma unroll
    for (int r = 0; r < 4; ++r) {
        const int row = ty + 8 * r;
        t[row][tx] = C3v[((size_t)(b * Sq + s0 + row)) * 512 + kv * 128 + d0 + tx];
    }
    __syncthreads();
#pragma unroll
    for (int r = 0; r < 4; ++r) {
        const int row = ty + 8 * r;
        Vt[((size_t)bk * HDn + d0 + row) * Sq + s0 + tx] = t[tx][row];
    }
}

// ------------- Block-cooperative MFMA flash attention (R5 structure + pk2) -------------
__global__ __launch_bounds__(256, 2) void fattn_kernel(
    const short* __restrict__ Qb, const short* __restrict__ Kb,
    const short* __restrict__ Vtb, short* __restrict__ AOb)
{
    __shared__ __align__(16) short Ks[2][64 * 128];   // [buf][perm key][dim], oct-swizzled
    __shared__ __align__(16) short Vs[2][128 * 64];   // [buf][dim][key], oct-swizzled

    const int tid  = threadIdx.x;
    const int w    = tid >> 6;
    const int lane = tid & 63;
    const int m16  = lane & 15;
    const int g4   = lane >> 4;

    // balanced mapping: blocks i and i+256 get complementary p
    const int i    = blockIdx.x;
    const int half = i >> 8;
    const int k4   = i & 15;
    const int p    = half ? k4 : 15 - k4;
    const int h    = (i >> 4) & 15;
    const int b    = i >> 8;
    const int kv   = h >> 2;

    const int htA = 31 - p;             // nested 64-row tiles: htA=31-p, htB=p
    const int nch = htA + 1;            // staged/computed chunks: 32-p
    const int qA  = htA * 64 + w * 16;
    const int qB  = p * 64 + w * 16;

    bf16x8 qfA[4], qfB[4];
    {
        const short* qpA = Qb + (((size_t)b * Hn + h) * Sq + qA + m16) * HDn + g4 * 8;
        const short* qpB = Qb + (((size_t)b * Hn + h) * Sq + qB + m16) * HDn + g4 * 8;
#pragma unroll
        for (int c = 0; c < 4; ++c) {
            qfA[c] = *(const bf16x8*)(qpA + c * 32);
            qfB[c] = *(const bf16x8*)(qpB + c * 32);
        }
    }

    const short* kbase = Kb  + ((size_t)b * KVn + kv) * Sq * HDn;
    const short* vbase = Vtb + ((size_t)b * KVn + kv) * (size_t)HDn * Sq;

    const short* gpK[4];
    const short* gpV[4];
#pragma unroll
    for (int r = 0; r < 4; ++r) {
        const int ci = r * 256 + tid;
        const int R  = ci >> 4, o = ci & 15;
        const int hf = (R >> 5) & 1, Rl = R & 31;
        const int phys = hf * 32 + ((Rl >> 2) & 3) * 8 + ((Rl >> 4) & 1) * 4 + (Rl & 3);
        gpK[r] = kbase + (size_t)phys * HDn + (o ^ (R & 7)) * 8;
        const int d = ci >> 3, ov = ci & 7;
        gpV[r] = vbase + (size_t)d * Sq + (ov ^ (d & 7)) * 8;
    }

    auto stage = [&](int ktE, int buf) {
#pragma unroll
        for (int r = 0; r < 4; ++r) {
            const short* gp = gpK[r] + (size_t)ktE * HDn;
            short* lp = &Ks[buf][(size_t)(r * 256 + w * 64) * 8];
            __builtin_amdgcn_global_load_lds(
                (const __attribute__((address_space(1))) void*)gp,
                (__attribute__((address_space(3))) void*)lp, 16, 0, 0);
        }
#pragma unroll
        for (int r = 0; r < 4; ++r) {
            const short* gp = gpV[r] + ktE;
            short* lp = &Vs[buf][(size_t)(r * 256 + w * 64) * 8];
            __builtin_amdgcn_global_load_lds(
                (const __attribute__((address_space(1))) void*)gp,
                (__attribute__((address_space(3))) void*)lp, 16, 0, 0);
        }
    };

    f32x4 OtA[8], OtB[8];
#pragma unroll
    for (int t = 0; t < 8; ++t) {
        OtA[t] = (f32x4){0.f, 0.f, 0.f, 0.f};
        OtB[t] = (f32x4){0.f, 0.f, 0.f, 0.f};
    }
    float mA = -1e30f, lA = 0.f, mB = -1e30f, lB = 0.f;

    stage(0, 0);
    int gpar = 0;

    // ================= dual phase: chunks 0..p =========
    for (int ch = 0; ch <= p; ++ch) {
        const int cur = gpar & 1; gpar ^= 1;
        const int kt  = ch << 6;

        __syncthreads();
        stage((ch + 1) << 6, cur ^ 1);

        const bool dgB = (ch == p);
        const short* KsC = Ks[cur];
        const short* VsC = Vs[cur];

        f32x4 sc0[4], sc1[4];
        __builtin_amdgcn_s_setprio(1);
#pragma unroll
        for (int f = 0; f < 4; ++f) {
            f32x4 a0 = (f32x4){0.f, 0.f, 0.f, 0.f};
            f32x4 a1 = (f32x4){0.f, 0.f, 0.f, 0.f};
            const int krow = f * 16 + m16;
#pragma unroll
            for (int c = 0; c < 4; ++c) {
                bf16x8 kf = *(const bf16x8*)&KsC[krow * 128 + (((c * 4 + g4) ^ (m16 & 7)) * 8)];
                a0 = __builtin_amdgcn_mfma_f32_16x16x32_bf16(kf, qfA[c], a0, 0, 0, 0);
                a1 = __builtin_amdgcn_mfma_f32_16x16x32_bf16(kf, qfB[c], a1, 0, 0, 0);
            }
            sc0[f] = a0; sc1[f] = a1;
        }
        __builtin_amdgcn_s_setprio(0);

        if (dgB) {
            const int qg = qB + m16;
#pragma unroll
            for (int f = 0; f < 4; ++f)
#pragma unroll
                for (int ii = 0; ii < 4; ++ii) {
                    const int kg = kt + (f >> 1) * 32 + g4 * 8 + (f & 1) * 4 + ii;
                    if (kg > qg) sc1[f][ii] = -1e30f;
                }
        }

        bf16x8 pf0[2], pf1[2];
        {
            float mx = sc0[0][0];
#pragma unroll
            for (int f = 0; f < 4; ++f)
#pragma unroll
                for (int ii = 0; ii < 4; ++ii) mx = fmaxf(mx, sc0[f][ii]);
            mx = fmaxf(mx, __shfl_xor(mx, 16));
            mx = fmaxf(mx, __shfl_xor(mx, 32));
            if (!__all(mx <= mA + 8.0f)) {
                const float nm = fmaxf(mA, mx);
                const float alpha = exp2f(mA - nm);
                mA = nm; lA *= alpha;
#pragma unroll
                for (int t = 0; t < 8; ++t)
#pragma unroll
                    for (int ii = 0; ii < 4; ++ii) OtA[t][ii] *= alpha;
            }
            float ps = 0.f;
#pragma unroll
            for (int f = 0; f < 4; ++f)
#pragma unroll
                for (int ii = 0; ii < 4; ++ii) {
                    sc0[f][ii] = exp2f(sc0[f][ii] - mA);
                    ps += sc0[f][ii];
                }
            ps += __shfl_xor(ps, 16);
            ps += __shfl_xor(ps, 32);
            lA += ps;
            u32x4 u;
            u[0] = pk2(sc0[0][0], sc0[0][1]); u[1] = pk2(sc0[0][2], sc0[0][3]);
            u[2] = pk2(sc0[1][0], sc0[1][1]); u[3] = pk2(sc0[1][2], sc0[1][3]);
            pf0[0] = *(bf16x8*)&u;
            u[0] = pk2(sc0[2][0], sc0[2][1]); u[1] = pk2(sc0[2][2], sc0[2][3]);
            u[2] = pk2(sc0[3][0], sc0[3][1]); u[3] = pk2(sc0[3][2], sc0[3][3]);
            pf0[1] = *(bf16x8*)&u;
        }
        {
            float mx = sc1[0][0];
#pragma unroll
            for (int f = 0; f < 4; ++f)
#pragma unroll
                for (int ii = 0; ii < 4; ++ii) mx = fmaxf(mx, sc1[f][ii]);
            mx = fmaxf(mx, __shfl_xor(mx, 16));
            mx = fmaxf(mx, __shfl_xor(mx, 32));
            if (!__all(mx <= mB + 8.0f)) {
                const float nm = fmaxf(mB, mx);
                const float alpha = exp2f(mB - nm);
                mB = nm; lB *= alpha;
#pragma unroll
                for (int t = 0; t < 8; ++t)
#pragma unroll
                    for (int ii = 0; ii < 4; ++ii) OtB[t][ii] *= alpha;
            }
            float ps = 0.f;
#pragma unroll
            for (int f = 0; f < 4; ++f)
#pragma unroll
                for (int ii = 0; ii < 4; ++ii) {
                    sc1[f][ii] = exp2f(sc1[f][ii] - mB);
                    ps += sc1[f][ii];
                }
            ps += __shfl_xor(ps, 16);
            ps += __shfl_xor(ps, 32);
            lB += ps;
            u32x4 u;
            u[0] = pk2(sc1[0][0], sc1[0][1]); u[1] = pk2(sc1[0][2], sc1[0][3]);
            u[2] = pk2(sc1[1][0], sc1[1][1]); u[3] = pk2(sc1[1][2], sc1[1][3]);
            pf1[0] = *(bf16x8*)&u;
            u[0] = pk2(sc1[2][0], sc1[2][1]); u[1] = pk2(sc1[2][2], sc1[2][3]);
            u[2] = pk2(sc1[3][0], sc1[3][1]); u[3] = pk2(sc1[3][2], sc1[3][3]);
            pf1[1] = *(bf16x8*)&u;
        }

        __builtin_amdgcn_s_setprio(1);
#pragma unroll
        for (int t = 0; t < 8; ++t) {
            const int d = t * 16 + m16;
            bf16x8 vfa = *(const bf16x8*)&VsC[d * 64 + ((g4 ^ (d & 7)) * 8)];
            bf16x8 vfb = *(const bf16x8*)&VsC[d * 64 + (((4 + g4) ^ (d & 7)) * 8)];
            OtA[t] = __builtin_amdgcn_mfma_f32_16x16x32_bf16(vfa, pf0[0], OtA[t], 0, 0, 0);
            OtA[t] = __builtin_amdgcn_mfma_f32_16x16x32_bf16(vfb, pf0[1], OtA[t], 0, 0, 0);
            OtB[t] = __builtin_amdgcn_mfma_f32_16x16x32_bf16(vfa, pf1[0], OtB[t], 0, 0, 0);
            OtB[t] = __builtin_amdgcn_mfma_f32_16x16x32_bf16(vfb, pf1[1], OtB[t], 0, 0, 0);
        }
        __builtin_amdgcn_s_setprio(0);
    }

    // tile B write
    {
        const float inv = 1.0f / lB;
        short* op = AOb + ((size_t)(b * Sq + qB + m16)) * (Hn * HDn) + h * HDn + g4 * 4;
#pragma unroll
        for (int t = 0; t < 8; ++t) {
            short4 o;
            o.x = f2b(OtB[t][0] * inv);
            o.y = f2b(OtB[t][1] * inv);
            o.z = f2b(OtB[t][2] * inv);
            o.w = f2b(OtB[t][3] * inv);
            *(short4*)(op + t * 16) = o;
        }
    }

    // ================= solo phase: chunks p+1..31-p =========
    for (int ch = p + 1; ch < nch; ++ch) {
        const int cur = gpar & 1; gpar ^= 1;
        const int kt  = ch << 6;

        __syncthreads();
        if (ch + 1 < nch) stage((ch + 1) << 6, cur ^ 1);

        const bool dgA = (ch == nch - 1);
        const short* KsC = Ks[cur];
        const short* VsC = Vs[cur];

        f32x4 sc[4];
        __builtin_amdgcn_s_setprio(1);
#pragma unroll
        for (int f = 0; f < 4; ++f) {
            f32x4 a = (f32x4){0.f, 0.f, 0.f, 0.f};
            const int krow = f * 16 + m16;
#pragma unroll
            for (int c = 0; c < 4; ++c) {
                bf16x8 kf = *(const bf16x8*)&KsC[krow * 128 + (((c * 4 + g4) ^ (m16 & 7)) * 8)];
                a = __builtin_amdgcn_mfma_f32_16x16x32_bf16(kf, qfA[c], a, 0, 0, 0);
            }
            sc[f] = a;
        }
        __builtin_amdgcn_s_setprio(0);

        if (dgA) {
            const int qg = qA + m16;
#pragma unroll
            for (int f = 0; f < 4; ++f)
#pragma unroll
                for (int ii = 0; ii < 4; ++ii) {
                    const int kg = kt + (f >> 1) * 32 + g4 * 8 + (f & 1) * 4 + ii;
                    if (kg > qg) sc[f][ii] = -1e30f;
                }
        }

        float mx = sc[0][0];
#pragma unroll
        for (int f = 0; f < 4; ++f)
#pragma unroll
            for (int ii = 0; ii < 4; ++ii) mx = fmaxf(mx, sc[f][ii]);
        mx = fmaxf(mx, __shfl_xor(mx, 16));
        mx = fmaxf(mx, __shfl_xor(mx, 32));
        if (!__all(mx <= mA + 8.0f)) {
            const float nm = fmaxf(mA, mx);
            const float alpha = exp2f(mA - nm);
            mA = nm; lA *= alpha;
#pragma unroll
            for (int t = 0; t < 8; ++t)
#pragma unroll
                for (int ii = 0; ii < 4; ++ii) OtA[t][ii] *= alpha;
        }
        float ps = 0.f;
#pragma unroll
        for (int f = 0; f < 4; ++f)
#pragma unroll
            for (int ii = 0; ii < 4; ++ii) {
                sc[f][ii] = exp2f(sc[f][ii] - mA);
                ps += sc[f][ii];
            }
        ps += __shfl_xor(ps, 16);
        ps += __shfl_xor(ps, 32);
        lA += ps;

        bf16x8 pf[2];
        {
            u32x4 u;
            u[0] = pk2(sc[0][0], sc[0][1]); u[1] = pk2(sc[0][2], sc[0][3]);
            u[2] = pk2(sc[1][0], sc[1][1]); u[3] = pk2(sc[1][2], sc[1][3]);
            pf[0] = *(bf16x8*)&u;
            u[0] = pk2(sc[2][0], sc[2][1]); u[1] = pk2(sc[2][2], sc[2][3]);
            u[2] = pk2(sc[3][0], sc[3][1]); u[3] = pk2(sc[3][2], sc[3][3]);
            pf[1] = *(bf16x8*)&u;
        }

        __builtin_amdgcn_s_setprio(1);
#pragma unroll
        for (int t = 0; t < 8; ++t) {
            const int d = t * 16 + m16;
            bf16x8 vfa = *(const bf16x8*)&VsC[d * 64 + ((g4 ^ (d & 7)) * 8)];
            bf16x8 vfb = *(const bf16x8*)&VsC[d * 64 + (((4 + g4) ^ (d & 7)) * 8)];
            OtA[t] = __builtin_amdgcn_mfma_f32_16x16x32_bf16(vfa, pf[0], OtA[t], 0, 0, 0);
            OtA[t] = __builtin_amdgcn_mfma_f32_16x16x32_bf16(vfb, pf[1], OtA[t], 0, 0, 0);
        }
        __builtin_amdgcn_s_setprio(0);
    }

    // tile A epilogue
    {
        const float inv = 1.0f / lA;
        short* op = AOb + ((size_t)(b * Sq + qA + m16)) * (Hn * HDn) + h * HDn + g4 * 4;
#pragma unroll
        for (int t = 0; t < 8; ++t) {
            short4 o;
            o.x = f2b(OtA[t][0] * inv);
            o.y = f2b(OtA[t][1] * inv);
            o.z = f2b(OtA[t][2] * inv);
            o.w = f2b(OtA[t][3] * inv);
            *(short4*)(op + t * 16) = o;
        }
    }
}

extern "C" void kernel_launch(void* const* d_in, const int* in_sizes, int n_in,
                              void* d_out, int out_size, void* d_ws, size_t ws_size,
                              hipStream_t stream)
{
    const float* x   = (const float*)d_in[0];
    const float* wq  = (const float*)d_in[1];
    const float* wk  = (const float*)d_in[2];
    const float* wv  = (const float*)d_in[3];
    const float* wo  = (const float*)d_in[4];
    const int* pos   = (const int*)d_in[6];
    float* out = (float*)d_out;

    const int M = Bsz * Sq;            // 4096
    const size_t nX  = (size_t)M * Dm; // 8388608

    short* xb    = (short*)d_ws;
    short* wqkvT = xb + nX;                       // 3072 x 2048
    short* woT   = wqkvT + (size_t)3072 * Dm;     // 2048 x 2048
    short* C3v   = woT + (size_t)Dm * Dm;         // 4096 x 512 bf16 (V only)
    short* Qb    = C3v + (size_t)M * 512;
    short* Kb    = Qb + nX;
    short* Vtb   = Kb + (size_t)Bsz * KVn * Sq * HDn;
    short* AOb   = Vtb + (size_t)Bsz * KVn * Sq * HDn;
    float* tcs   = (float*)(AOb + nX);            // 64 x 4096 x 2 fp32 (2 MB)

    const float qscale = 0.08838834764831845f * 1.4426950408889634f;

    // --- fused conversions + rope table (1 launch) ---
    prep_kernel<<<NB_F2B + NB_WC + NB_TCS, 256, 0, stream>>>(
        x, xb, wq, wk, wv, wo, wqkvT, woT, pos, tcs);

    // --- QKV projection with fused in-register RoPE epilogue ---
    gemm_qkv_kernel<<<dim3(3072 / 128, M / 128), 256, 0, stream>>>(
        xb, wqkvT, Qb, Kb, C3v, tcs, qscale);

    // --- V transpose ---
    vconv_kernel<<<dim3(Sq / 32, HDn / 32, Bsz * KVn), dim3(32, 8), 0, stream>>>(
        C3v, Vtb);

    // --- attention: 512 blocks, nested dual-tile (R5 structure + pk2) ---
    fattn_kernel<<<Bsz * Hn * 16, 256, 0, stream>>>(Qb, Kb, Vtb, AOb);

    // --- output projection (fp32 out, XCD-swizzled) ---
    gemm_o_kernel<<<dim3(Dm / 128, M / 128), 256, 0, stream>>>(
        AOb, woT, out, M, Dm, Dm);
}